// Round 5
// baseline (343.534 us; speedup 1.0000x reference)
//
#include <hip/hip_runtime.h>

// gConv3d separable factorization:
//   q[n,o,b,h,w]   = sum_{c,f} x[c, n+f, h, w] * weight[o,c,f,b]        (K=216)
//   s[n,g,o,ii,jj] = sum_{b,u,v} q[n,o,b,ii+u,jj+v] * basisT[(b,u,v)][g] (K=63)
//   out[g*8+o, xo+1,yo+1,zo+1, h, w] = s[n, T(g,h,w), o, clip(h)-1, clip(w)-1] + bias_sum[o]
// T(g,h,w) = (g+1)%12 on the (h,w) border, else g. Non-interior xyz = 0.
//
// R5 changes vs R4 (R4: 166us, VALUBusy 50% vs ~64us VALU floor -> stage-1
// load-latency stalls; VGPR=36 means compiler kept few loads in flight):
//  - stage 1 loads all 27 taps of a channel into xv[27] before the FMA block:
//    27 loads in flight, 756 FMA-issue-cyc per wait window >> ~200cyc L2 lat.
//  - __launch_bounds__(320,8) pins VGPR<=64: keeps 8 waves/EU so occupancy
//    stays LDS-limited at 6 blocks/CU (30 waves). 65-73 VGPR would drop to 5.
//  - zero-fill moved after __syncthreads(): its stores overlap stage-2
//    (lgkm-only) work instead of sitting in stage-1's vmcnt FIFO ahead of
//    x-load waits. Keyed by `logical` (pad blocks early-return, own no share).

#define HW 320
#define OG 2          // o's per block (4 blocks per n)
#define NLOG 2916     // 729 n * 4 o-quarters
#define NPAD 2928     // 8 * 366

__global__ __launch_bounds__(320, 8) void fused_kernel(
    const float* __restrict__ x, const float* __restrict__ weight,
    const float* __restrict__ bias, const float* __restrict__ basis,
    float* __restrict__ out)
{
    __shared__ float qs[OG * 7 * HW];   // 17920 B
    __shared__ float bT[63 * 12];       // 3024 B; bT[(b,u,v)][g] = basis[g][(b,u,v)]

    const int tid = threadIdx.x;

    // XCD-aware swizzle: contiguous logical range per XCD; all 4 o-blocks of
    // one n stay on the same XCD (they share all 216 x taps).
    const int xcd  = blockIdx.x & 7;
    const int slot = blockIdx.x >> 3;
    const int logical = xcd * (NPAD / 8) + slot;
    if (logical >= NLOG) return;

    const int n  = logical >> 2;
    const int o0 = (logical & 3) * OG;
    const int xo = n / 81;
    const int rem = n - xo * 81;
    const int yo = rem / 9;
    const int zo = rem - yo * 9;

    // stage basis transpose into LDS (756 floats)
    for (int i = tid; i < 756; i += 320) {
        int j = i / 12;          // (b,u,v) flat
        int g = i - j * 12;
        bT[i] = basis[g * 63 + j];
    }

    // ---------------- stage 1: q into registers ----------------
    float acc[OG * 7];
    #pragma unroll
    for (int i = 0; i < OG * 7; ++i) acc[i] = 0.f;

    const float* xb = x + ((xo * 12 + yo) * 12 + zo) * HW + tid;

    #pragma unroll 1
    for (int c = 0; c < 8; ++c) {
        const float* xc = xb + c * 1728 * HW;
        // batch: 27 loads in flight (compile-time offsets)
        float xv[27];
        #pragma unroll
        for (int t = 0; t < 27; ++t) {
            const int fi = t / 9, fj = (t / 3) % 3, fk = t % 3;
            xv[t] = xc[(fi * 144 + fj * 12 + fk) * HW];
        }
        const float* wc = weight + o0 * 1512 + c * 189;  // uniform -> s_load
        #pragma unroll
        for (int t = 0; t < 27; ++t) {
            const int fi = t / 9, fj = (t / 3) % 3, fk = t % 3;
            const float* wp = wc + fi * 63 + fj * 21 + fk * 7;
            #pragma unroll
            for (int oo = 0; oo < OG; ++oo)
                #pragma unroll
                for (int b = 0; b < 7; ++b)
                    acc[oo * 7 + b] = fmaf(xv[t], wp[oo * 1512 + b], acc[oo * 7 + b]);
        }
    }

    #pragma unroll
    for (int i = 0; i < OG * 7; ++i) qs[i * HW + tid] = acc[i];
    __syncthreads();

    // ---- border zero-fill (overlaps stage 2; vmcnt-only, stage 2 is lgkm) ----
    {
        float4* out4 = (float4*)out;
        const float4 z = make_float4(0.f, 0.f, 0.f, 0.f);
        for (int s = logical * 320 + tid; s < 96 * 1728 * 80; s += NLOG * 320) {
            int row = s / 80;                      // go*1728 + xyz
            int xyz = row - (row / 1728) * 1728;
            int xi = xyz / 144;
            int r2 = xyz - xi * 144;
            int yi = r2 / 12;
            int zi = r2 - yi * 12;
            if (!((unsigned)(xi - 1) < 9u && (unsigned)(yi - 1) < 9u &&
                  (unsigned)(zi - 1) < 9u))
                out4[s] = z;
        }
    }

    // ---------------- stage 2: one pass over 63 taps, both oo ----------------
    const int h = tid / 40;
    const int w = tid - h * 40;
    const int ii = min(max(h, 1), 6) - 1;    // 0..5
    const int jj = min(max(w, 1), 38) - 1;   // 0..37
    const bool border = (h == 0) | (h == 7) | (w == 0) | (w == 39);
    const int base_hw = ii * 40 + jj;

    // bias sums early (SMEM loads issue ahead of the LDS loop)
    float bs[OG];
    #pragma unroll
    for (int oo = 0; oo < OG; ++oo) {
        float t = 0.f;
        #pragma unroll
        for (int i = 0; i < 27; ++i) t += bias[(o0 + oo) * 27 + i];
        bs[oo] = t;
    }

    float s[OG][12];
    #pragma unroll
    for (int oo = 0; oo < OG; ++oo)
        #pragma unroll
        for (int g = 0; g < 12; ++g) s[oo][g] = 0.f;

    #pragma unroll 1
    for (int b = 0; b < 7; ++b) {
        #pragma unroll
        for (int uv = 0; uv < 9; ++uv) {
            const int u = uv / 3, v = uv - (uv / 3) * 3;  // compile-time (unrolled)
            const float* bv = bT + (b * 9 + uv) * 12;     // same-addr broadcast reads
            float qw[OG];
            #pragma unroll
            for (int oo = 0; oo < OG; ++oo)
                qw[oo] = qs[(oo * 7 + b) * HW + base_hw + u * 40 + v];
            #pragma unroll
            for (int oo = 0; oo < OG; ++oo)
                #pragma unroll
                for (int g = 0; g < 12; ++g)
                    s[oo][g] = fmaf(qw[oo], bv[g], s[oo][g]);
        }
    }

    const int out_xyz = ((xo + 1) * 144 + (yo + 1) * 12 + (zo + 1)) * HW + tid;

    #pragma unroll
    for (int oo = 0; oo < OG; ++oo)
        #pragma unroll
        for (int g = 0; g < 12; ++g) {
            float val = (border ? s[oo][(g + 1) % 12] : s[oo][g]) + bs[oo];
            out[(g * 8 + o0 + oo) * (1728 * HW) + out_xyz] = val;
        }
}

extern "C" void kernel_launch(void* const* d_in, const int* in_sizes, int n_in,
                              void* d_out, int out_size, void* d_ws, size_t ws_size,
                              hipStream_t stream)
{
    const float* x      = (const float*)d_in[0];
    const float* weight = (const float*)d_in[1];
    const float* bias   = (const float*)d_in[2];
    const float* basis  = (const float*)d_in[3];
    float* out = (float*)d_out;

    fused_kernel<<<NPAD, 320, 0, stream>>>(x, weight, bias, basis, out);
}